// Round 4
// baseline (202.320 us; speedup 1.0000x reference)
//
#include <hip/hip_runtime.h>

typedef unsigned short u16;
typedef __attribute__((ext_vector_type(8))) short shortx8;
typedef __attribute__((ext_vector_type(4))) float floatx4;
typedef __attribute__((ext_vector_type(2))) float floatx2;
typedef __attribute__((ext_vector_type(2))) unsigned uintx2;
typedef __attribute__((ext_vector_type(4))) unsigned uintx4;

#define GLD16(gp, lp) __builtin_amdgcn_global_load_lds( \
    (__attribute__((address_space(1))) void*)(gp), \
    (__attribute__((address_space(3))) void*)(lp), 16, 0, 0)

#define BAR() __builtin_amdgcn_s_barrier()
#define LGKM0() do { asm volatile("s_waitcnt lgkmcnt(0)" ::: "memory"); \
                     __builtin_amdgcn_sched_barrier(0); } while (0)
#define VMCNT0() do { asm volatile("s_waitcnt vmcnt(0)" ::: "memory"); \
                      __builtin_amdgcn_sched_barrier(0); } while (0)
#define VMCNT4() do { asm volatile("s_waitcnt vmcnt(4)" ::: "memory"); \
                      __builtin_amdgcn_sched_barrier(0); } while (0)

__device__ __forceinline__ u16 f2bf(float f) {
  union { float f; unsigned u; } v; v.f = f;
  unsigned r = v.u + 0x7FFFu + ((v.u >> 16) & 1u);
  return (u16)(r >> 16);
}

// pack two f32 -> bf16x2 in one u32 (low = a, high = b)
__device__ __forceinline__ unsigned pkbf(float a, float b) {
#if __has_builtin(__builtin_amdgcn_cvt_pk_bf16_f32)
  auto r = __builtin_amdgcn_cvt_pk_bf16_f32(a, b);
  return __builtin_bit_cast(unsigned, r);
#else
  union { float f; unsigned u; } x, y; x.f = a; y.f = b;
  return __builtin_amdgcn_perm(y.u + 0x8000u, x.u + 0x8000u, 0x07060302u);
#endif
}

// ---------------- prep: cast x -> bf16  +  transpose-cast 4 weights ----------------
__global__ __launch_bounds__(256) void prep_kernel(const float* __restrict__ x,
                                                   u16* __restrict__ xb,
                                                   const float* __restrict__ Wq,
                                                   const float* __restrict__ Wk,
                                                   const float* __restrict__ Wv,
                                                   const float* __restrict__ Wo,
                                                   u16* __restrict__ Wt) {
  __shared__ u16 tile[32][33];
  int bid = blockIdx.x;
  int tid = threadIdx.x;
  if (bid < 4096) {
    int i = bid * 256 + tid;
    float4 v = ((const float4*)x)[i];
    uintx2 o;
    o.x = pkbf(v.x, v.y);
    o.y = pkbf(v.z, v.w);
    ((uintx2*)xb)[i] = o;
  } else {
    int block = bid - 4096;
    int mat = block >> 10;
    int rem = block & 1023;
    const float* W = (mat == 0) ? Wq : (mat == 1) ? Wk : (mat == 2) ? Wv : Wo;
    u16* dst = Wt + (size_t)mat * 1024 * 1024;
    int n0 = (rem & 31) * 32, k0 = (rem >> 5) * 32;
    int tx = tid & 31, ty = tid >> 5;
    for (int i = 0; i < 4; ++i)
      tile[ty + i * 8][tx] = f2bf(W[(size_t)(k0 + ty + i * 8) * 1024 + n0 + tx]);
    __syncthreads();
    for (int i = 0; i < 4; ++i)
      dst[(size_t)(n0 + ty + i * 8) * 1024 + k0 + tx] = tile[tx][ty + i * 8];
  }
}

// ---------------- QKV projection: 256x256-tile 8-phase schedule ----------------
template <int MIB>
__device__ __forceinline__ void qkv_lda(const u16* Ah, int lrow, int lcol,
                                        shortx8 (&afr)[2][2]) {
#pragma unroll
  for (int j = 0; j < 2; ++j) {
    int rm = (MIB + j) * 16 + lcol;
#pragma unroll
    for (int kk = 0; kk < 2; ++kk)
      afr[j][kk] = *(const shortx8*)&Ah[rm * 64 + (((kk * 4 + lrow) ^ (rm & 7)) * 8)];
  }
}

template <int MIB>
__device__ __forceinline__ void qkv_mfma(floatx4 (&acc)[8][4],
                                         const shortx8 (&afr)[2][2],
                                         const shortx8 (&bfr)[4][2]) {
#pragma unroll
  for (int kk = 0; kk < 2; ++kk)
#pragma unroll
    for (int j = 0; j < 2; ++j)
#pragma unroll
      for (int ni = 0; ni < 4; ++ni)
        acc[MIB + j][ni] = __builtin_amdgcn_mfma_f32_16x16x32_bf16(
            afr[j][kk], bfr[ni][kk], acc[MIB + j][ni], 0, 0, 0);
}

__global__ __launch_bounds__(512, 2) void qkv_gemm(const u16* __restrict__ xb,
                                                   const u16* __restrict__ Wt,
                                                   const float* __restrict__ bq,
                                                   const float* __restrict__ bk,
                                                   const float* __restrict__ bv,
                                                   u16* __restrict__ Qh,
                                                   u16* __restrict__ Kh,
                                                   u16* __restrict__ Vth) {
  __shared__ u16 lds[65536];   // dbuf d: A at d*32768, B at d*32768+16384 (u16 units)
  const int tid = threadIdx.x;
  const int wave = tid >> 6, lane = tid & 63;
  const int lrow = lane >> 4, lcol = lane & 15;
  const int wm = wave >> 2, wn = wave & 3;
  const int m0 = blockIdx.x * 256;
  const int nt = blockIdx.y;
  const int mat = nt >> 2;
  const int n0 = (nt & 3) * 256;
  const u16* Ag = xb;
  const u16* Bg = Wt + (size_t)mat * 1048576;

  const u16* sa[2][2];
  const u16* sb[2][2];
#pragma unroll
  for (int h = 0; h < 2; ++h)
#pragma unroll
    for (int l = 0; l < 2; ++l) {
      int g = (l * 8 + wave) * 64 + lane;
      int r = g >> 3, c = g & 7;
      int cc = (c ^ (r & 7)) * 8;
      sa[h][l] = Ag + (size_t)(m0 + h * 128 + r) * 1024 + cc;
      sb[h][l] = Bg + (size_t)(n0 + h * 128 + r) * 1024 + cc;
    }

  floatx4 acc[8][4];
#pragma unroll
  for (int mi = 0; mi < 8; ++mi)
#pragma unroll
    for (int ni = 0; ni < 4; ++ni)
      acc[mi][ni] = (floatx4){0.f, 0.f, 0.f, 0.f};

  // prologue: stage K-tile 0 into dbuf 0
#pragma unroll
  for (int h = 0; h < 2; ++h)
#pragma unroll
    for (int l = 0; l < 2; ++l) {
      GLD16(sa[h][l], lds + h * 8192 + (l * 8 + wave) * 512);
      GLD16(sb[h][l], lds + 16384 + h * 8192 + (l * 8 + wave) * 512);
    }
  VMCNT0();
  BAR();

#pragma unroll 2
  for (int t = 0; t < 16; ++t) {
    const int rb = t & 1, wb = rb ^ 1;
    const u16* Ah = lds + rb * 32768 + wm * 8192;
    const u16* Bh = lds + rb * 32768 + 16384 + (wn >> 1) * 8192;
    u16* Aw = lds + wb * 32768;
    u16* Bw = lds + wb * 32768 + 16384;

    // ---- phase 0: stage A halves of t+1; read all B-frags + A-frags mi 0-1
    if (t < 15) {
      int k64 = (t + 1) * 64;
#pragma unroll
      for (int l = 0; l < 2; ++l) {
        GLD16(sa[0][l] + k64, Aw + (l * 8 + wave) * 512);
        GLD16(sa[1][l] + k64, Aw + 8192 + (l * 8 + wave) * 512);
      }
    }
    shortx8 bfr[4][2];
#pragma unroll
    for (int ni = 0; ni < 4; ++ni) {
      int rn = (wn & 1) * 64 + ni * 16 + lcol;
#pragma unroll
      for (int kk = 0; kk < 2; ++kk)
        bfr[ni][kk] = *(const shortx8*)&Bh[rn * 64 + (((kk * 4 + lrow) ^ (rn & 7)) * 8)];
    }
    {
      shortx8 afr[2][2];
      qkv_lda<0>(Ah, lrow, lcol, afr);
      BAR();
      LGKM0();
      __builtin_amdgcn_s_setprio(1);
      qkv_mfma<0>(acc, afr, bfr);
      __builtin_amdgcn_s_setprio(0);
      BAR();
    }
    // ---- phase 1: stage B halves of t+1; A-frags mi 2-3
    if (t < 15) {
      int k64 = (t + 1) * 64;
#pragma unroll
      for (int l = 0; l < 2; ++l) {
        GLD16(sb[0][l] + k64, Bw + (l * 8 + wave) * 512);
        GLD16(sb[1][l] + k64, Bw + 8192 + (l * 8 + wave) * 512);
      }
    }
    {
      shortx8 afr[2][2];
      qkv_lda<2>(Ah, lrow, lcol, afr);
      BAR();
      LGKM0();
      __builtin_amdgcn_s_setprio(1);
      qkv_mfma<2>(acc, afr, bfr);
      __builtin_amdgcn_s_setprio(0);
      BAR();
    }
    // ---- phase 2: A-frags mi 4-5
    {
      shortx8 afr[2][2];
      qkv_lda<4>(Ah, lrow, lcol, afr);
      BAR();
      LGKM0();
      __builtin_amdgcn_s_setprio(1);
      qkv_mfma<4>(acc, afr, bfr);
      __builtin_amdgcn_s_setprio(0);
      BAR();
    }
    // ---- phase 3: A-frags mi 6-7; boundary vmcnt drains t+1 loads (~3 phases old)
    {
      shortx8 afr[2][2];
      qkv_lda<6>(Ah, lrow, lcol, afr);
      BAR();
      LGKM0();
      __builtin_amdgcn_s_setprio(1);
      qkv_mfma<6>(acc, afr, bfr);
      __builtin_amdgcn_s_setprio(0);
      VMCNT0();
      BAR();
    }
  }

  // ---------------- epilogue ----------------
  const float* bias = (mat == 0) ? bq : (mat == 1) ? bk : bv;
  const float qscale = 0.18033688011f;  // log2(e)/8

  if (mat < 2) {
    // transpose-pack through the dead 128KiB LDS -> packed 16B stores
    u16* dst = (mat == 0) ? Qh : Kh;
    float sc = (mat == 0) ? qscale : 1.0f;
#pragma unroll
    for (int mi = 0; mi < 8; ++mi) {
      int mb = wm * 128 + mi * 16 + lrow * 4;
#pragma unroll
      for (int ni = 0; ni < 4; ++ni) {
        int n = wn * 64 + ni * 16 + lcol;
        float bval = bias[n0 + n];
#pragma unroll
        for (int r = 0; r < 4; ++r) {
          int m = mb + r;
          lds[m * 256 + (((n >> 3) ^ (m & 31)) * 8) + (n & 7)] =
              f2bf((acc[mi][ni][r] + bval) * sc);
        }
      }
    }
    __syncthreads();
    int row = tid >> 1, half = tid & 1;
    int m = m0 + row;
    int bb = m >> 11, s = m & 2047;
#pragma unroll
    for (int i = 0; i < 16; ++i) {
      int cg = half * 16 + i;                    // column granule (8 cols)
      int pg = cg ^ (row & 31);
      shortx8 v = *(const shortx8*)&lds[row * 256 + pg * 8];
      int ng = n0 + cg * 8;
      int hh = ng >> 6, d = ng & 63;
      *(shortx8*)&dst[((size_t)(bb * 16 + hh) * 2048 + s) * 64 + d] = v;
    }
  } else {
    // V: transposed scattered stores (head-major [bh][d][s])
#pragma unroll
    for (int mi = 0; mi < 8; ++mi) {
      int mbase = m0 + wm * 128 + mi * 16 + lrow * 4;
      int bb = mbase >> 11, s = mbase & 2047;
#pragma unroll
      for (int ni = 0; ni < 4; ++ni) {
        int n = n0 + wn * 64 + ni * 16 + lcol;
        float bval = bias[n];
        int hh = n >> 6, d = n & 63;
        uintx2 pk;
        pk.x = pkbf(acc[mi][ni][0] + bval, acc[mi][ni][1] + bval);
        pk.y = pkbf(acc[mi][ni][2] + bval, acc[mi][ni][3] + bval);
        *(uintx2*)&Vth[((size_t)(bb * 16 + hh) * 64 + d) * 2048 + s] = pk;
      }
    }
  }
}

// ---------------- output projection: aout = ctx @ Wo^T + bo (fp32) ----------------
__global__ __launch_bounds__(256) void out_gemm(const u16* __restrict__ ctx,
                                                const u16* __restrict__ Wot,
                                                const float* __restrict__ bo,
                                                float* __restrict__ aout) {
  __shared__ u16 As[128 * 64];
  __shared__ u16 Bs[64 * 64];
  int m0 = blockIdx.x * 128;
  int n0 = blockIdx.y * 64;
  const int tid = threadIdx.x;
  const int wave = tid >> 6, lane = tid & 63;
  const int lrow = lane >> 4, lcol = lane & 15;
  const int wm = wave >> 1, wn = wave & 1;

  floatx4 acc[4][2];
  for (int mi = 0; mi < 4; ++mi)
    for (int ni = 0; ni < 2; ++ni)
      acc[mi][ni] = (floatx4){0.f, 0.f, 0.f, 0.f};

  const u16* ap[4];
  const u16* bp[2];
  for (int l = 0; l < 4; ++l) {
    int g = (l * 4 + wave) * 64 + lane;
    int r = g >> 3, c = g & 7;
    ap[l] = ctx + (size_t)(m0 + r) * 1024 + (c ^ (r & 7)) * 8;
  }
  for (int l = 0; l < 2; ++l) {
    int g = (l * 4 + wave) * 64 + lane;
    int r = g >> 3, c = g & 7;
    bp[l] = Wot + (size_t)(n0 + r) * 1024 + (c ^ (r & 7)) * 8;
  }

  for (int k0 = 0; k0 < 1024; k0 += 64) {
    __syncthreads();
    for (int l = 0; l < 4; ++l) { GLD16(ap[l], As + (l * 4 + wave) * 512); ap[l] += 64; }
    for (int l = 0; l < 2; ++l) { GLD16(bp[l], Bs + (l * 4 + wave) * 512); bp[l] += 64; }
    __syncthreads();
    for (int kk = 0; kk < 2; ++kk) {
      shortx8 af[4], bf[2];
      for (int mi = 0; mi < 4; ++mi) {
        int row = wm * 64 + mi * 16 + lcol;
        int gr = (kk * 4 + lrow) ^ (row & 7);
        af[mi] = *(const shortx8*)&As[row * 64 + gr * 8];
      }
      for (int ni = 0; ni < 2; ++ni) {
        int row = wn * 32 + ni * 16 + lcol;
        int gr = (kk * 4 + lrow) ^ (row & 7);
        bf[ni] = *(const shortx8*)&Bs[row * 64 + gr * 8];
      }
      for (int mi = 0; mi < 4; ++mi)
        for (int ni = 0; ni < 2; ++ni)
          acc[mi][ni] = __builtin_amdgcn_mfma_f32_16x16x32_bf16(af[mi], bf[ni], acc[mi][ni], 0, 0, 0);
    }
  }

  for (int mi = 0; mi < 4; ++mi) {
    int mbase = m0 + wm * 64 + mi * 16 + lrow * 4;
    for (int ni = 0; ni < 2; ++ni) {
      int n = n0 + wn * 32 + ni * 16 + lcol;
      float bval = bo[n];
      for (int r = 0; r < 4; ++r)
        aout[(size_t)(mbase + r) * 1024 + n] = acc[mi][ni][r] + bval;
    }
  }
}

// ---------------- flash attention ----------------
// grid (32_bh, 16_qt), 256 threads = 4 waves, each owning 32 q-rows (2 q-sets).
// T4 counted-vmcnt schedule: per-iter raw s_barrier + lgkmcnt(0) only (LDS
// ordering); NO vmcnt(0) drain in the main loop. At iter top the VMEM queue is
// [K(i)x2, Vg(i+1)x2, K(i+1)x2] = 6; vmcnt(4) retires exactly the K tile being
// consumed while this iter's 4 fresh loads stay in flight across the barrier.
// Race audit: the single end-of-iter barrier separates generation-i LDS reads
// from generation-(i+2) writes (GLD16 issue and V ds_write are post-barrier,
// one full iteration after the last reader); V ds_writes drained by lgkmcnt(0)
// before the barrier; vmcnt retires in issue order so vmcnt(4) makes the K LDS
// writes visible (m201 contract). P never touches LDS (QK^T accumulator pairs
// feed the PV B-fragment in-order; V staged with inverse-permuted key columns).
// Row-sums via ones-MFMA.
__global__ __launch_bounds__(256, 2) void attn_kernel(const u16* __restrict__ Qh,
                                                      const u16* __restrict__ Kh,
                                                      const u16* __restrict__ Vth,
                                                      u16* __restrict__ ctx) {
  __shared__ u16 QPs[128 * 64];     // Q tile staging (dead after prologue)
  __shared__ u16 Ks[2][64 * 64];
  __shared__ u16 Vs[2][64 * 64];

  int bh = blockIdx.x;
  int b = bh >> 4, h = bh & 15;
  int q0 = blockIdx.y * 128;
  int tid = threadIdx.x;
  int wave = tid >> 6, lane = tid & 63;
  int lrow = lane >> 4, lcol = lane & 15;

  const u16* Qg = Qh + ((size_t)bh * 2048 + q0) * 64;
#pragma unroll
  for (int l = 0; l < 4; ++l) {
    int g = (l * 4 + wave) * 64 + lane;
    int r = g >> 3, c = g & 7;
    GLD16(Qg + r * 64 + ((c ^ (r & 7)) * 8), QPs + (l * 4 + wave) * 512);
  }

  const u16* Kbase = Kh + (size_t)bh * 2048 * 64;
  const u16* Vbase = Vth + (size_t)bh * 64 * 2048;

  const u16* kp[2];
  const u16* vp[2];
  int offA[2], offB[2];
#pragma unroll
  for (int l = 0; l < 2; ++l) {
    int g = (l * 4 + wave) * 64 + lane;
    int gr = g >> 3, gc = g & 7;
    kp[l] = Kbase + (size_t)gr * 64 + ((gc ^ (gr & 7)) * 8);
    vp[l] = Vbase + (size_t)gr * 2048 + gc * 8;
    int hh = gc >> 2, ct = gc & 3;
    int ua = 4 * (ct & 1) + (ct >> 1);
    int chunkA = hh * 4 + (ua >> 1);
    offA[l] = gr * 128 + ((chunkA ^ (gr & 7)) * 16) + (ua & 1) * 8;
    offB[l] = gr * 128 + (((chunkA + 1) ^ (gr & 7)) * 16) + (ua & 1) * 8;
  }

  // prologue: tile 0 (full drain once via __syncthreads is fine here)
  {
    float4 v0 = *(const float4*)vp[0];
    float4 v1 = *(const float4*)vp[1];
    vp[0] += 64; vp[1] += 64;
    GLD16(kp[0], (u16*)Ks + wave * 512);
    GLD16(kp[1], (u16*)Ks + (4 + wave) * 512);
    kp[0] += 4096; kp[1] += 4096;
    char* vb = (char*)Vs;
    *(floatx2*)(vb + offA[0]) = (floatx2){v0.x, v0.y};
    *(floatx2*)(vb + offB[0]) = (floatx2){v0.z, v0.w};
    *(floatx2*)(vb + offA[1]) = (floatx2){v1.x, v1.y};
    *(floatx2*)(vb + offB[1]) = (floatx2){v1.z, v1.w};
  }
  __syncthreads();

  // hoist Q fragments (B-operand: n = q = lane&15); wave owns q-rows wave*32..+31
  shortx8 qf[2][2];
#pragma unroll
  for (int s = 0; s < 2; ++s)
#pragma unroll
    for (int kk = 0; kk < 2; ++kk) {
      int row = wave * 32 + s * 16 + lcol;
      int grr = (kk * 4 + lrow) ^ (row & 7);
      qf[s][kk] = *(const shortx8*)&QPs[row * 64 + grr * 8];
    }

  const short one_bf = (short)0x3F80;
  const shortx8 ones8 = {one_bf, one_bf, one_bf, one_bf, one_bf, one_bf, one_bf, one_bf};

  floatx4 o[2][4];
  floatx4 lacc[2];
#pragma unroll
  for (int s = 0; s < 2; ++s) {
    lacc[s] = (floatx4){0.f, 0.f, 0.f, 0.f};
#pragma unroll
    for (int dt = 0; dt < 4; ++dt) o[s][dt] = (floatx4){0.f, 0.f, 0.f, 0.f};
  }

#pragma unroll 1
  for (int i = 0; i < 32; ++i) {
    int cur = i & 1;
    float4 v0, v1;
    if (i < 31) {
      v0 = *(const float4*)vp[0];   // issued before K GLD: vreg wait leaves K in flight
      v1 = *(const float4*)vp[1];
      vp[0] += 64; vp[1] += 64;
      GLD16(kp[0], (u16*)Ks + (cur ^ 1) * 4096 + wave * 512);
      GLD16(kp[1], (u16*)Ks + (cur ^ 1) * 4096 + (4 + wave) * 512);
      kp[0] += 4096; kp[1] += 4096;
      VMCNT4();   // K(i) landed; this iter's 4 loads remain in flight
    } else {
      VMCNT0();   // last iter: drain K(31)
    }

    // S^T[key][q] for this wave's 2x16 q-cols x 64 keys; kf shared across q-sets
    floatx4 sc[2][4];
#pragma unroll
    for (int s = 0; s < 2; ++s)
#pragma unroll
      for (int kt = 0; kt < 4; ++kt)
        sc[s][kt] = (floatx4){0.f, 0.f, 0.f, 0.f};
    __builtin_amdgcn_s_setprio(1);
#pragma unroll
    for (int kk = 0; kk < 2; ++kk) {
#pragma unroll
      for (int kt = 0; kt < 4; ++kt) {
        int row = kt * 16 + lcol;
        int grr = (kk * 4 + lrow) ^ (row & 7);
        shortx8 kf = *(const shortx8*)&Ks[cur][row * 64 + grr * 8];
        sc[0][kt] = __builtin_amdgcn_mfma_f32_16x16x32_bf16(kf, qf[0][kk], sc[0][kt], 0, 0, 0);
        sc[1][kt] = __builtin_amdgcn_mfma_f32_16x16x32_bf16(kf, qf[1][kk], sc[1][kt], 0, 0, 0);
      }
    }
    __builtin_amdgcn_s_setprio(0);

    // P = exp2(S^T) (Q pre-scaled); pack in-register into B-fragments.
    shortx8 pf[2][2];
#pragma unroll
    for (int s = 0; s < 2; ++s) {
      float p[4][4];
#pragma unroll
      for (int kt = 0; kt < 4; ++kt)
#pragma unroll
        for (int r = 0; r < 4; ++r)
          p[kt][r] = __builtin_amdgcn_exp2f(sc[s][kt][r]);
#pragma unroll
      for (int kk = 0; kk < 2; ++kk) {
        uintx4 w;
        w.x = pkbf(p[2 * kk][0], p[2 * kk][1]);
        w.y = pkbf(p[2 * kk][2], p[2 * kk][3]);
        w.z = pkbf(p[2 * kk + 1][0], p[2 * kk + 1][1]);
        w.w = pkbf(p[2 * kk + 1][2], p[2 * kk + 1][3]);
        pf[s][kk] = __builtin_bit_cast(shortx8, w);
      }
    }

    // stage next V tile (permuted columns); vreg use waits vmcnt(2) (K stays in flight)
    if (i < 31) {
      char* vb = (char*)Vs + (cur ^ 1) * 8192;
      *(floatx2*)(vb + offA[0]) = (floatx2){v0.x, v0.y};
      *(floatx2*)(vb + offB[0]) = (floatx2){v0.z, v0.w};
      *(floatx2*)(vb + offA[1]) = (floatx2){v1.x, v1.y};
      *(floatx2*)(vb + offB[1]) = (floatx2){v1.z, v1.w};
    }

    // O^T += V^T P^T; row-sums l += ones * P^T (same pf operand); vf shared
    __builtin_amdgcn_s_setprio(1);
#pragma unroll
    for (int kk = 0; kk < 2; ++kk) {
      lacc[0] = __builtin_amdgcn_mfma_f32_16x16x32_bf16(ones8, pf[0][kk], lacc[0], 0, 0, 0);
      lacc[1] = __builtin_amdgcn_mfma_f32_16x16x32_bf16(ones8, pf[1][kk], lacc[1], 0, 0, 0);
#pragma unroll
      for (int dt = 0; dt < 4; ++dt) {
        int row = dt * 16 + lcol;
        int grr = (kk * 4 + lrow) ^ (row & 7);
        shortx8 vf = *(const shortx8*)&Vs[cur][row * 64 + grr * 8];
        o[0][dt] = __builtin_amdgcn_mfma_f32_16x16x32_bf16(vf, pf[0][kk], o[0][dt], 0, 0, 0);
        o[1][dt] = __builtin_amdgcn_mfma_f32_16x16x32_bf16(vf, pf[1][kk], o[1][dt], 0, 0, 0);
      }
    }
    __builtin_amdgcn_s_setprio(0);
    LGKM0();   // V ds_writes visible to all waves before they cross the barrier
    BAR();     // raw barrier: in-flight global loads are NOT drained
  }

  // epilogue: l = lacc[s][0] (all regs equal = column sum), O /= l, packed 8B stores
#pragma unroll
  for (int s = 0; s < 2; ++s) {
    float inv = 1.0f / lacc[s][0];
    int sq = q0 + wave * 32 + s * 16 + lcol;
    u16* dst = ctx + (size_t)(b * 2048 + sq) * 1024 + h * 64 + lrow * 4;
#pragma unroll
    for (int dt = 0; dt < 4; ++dt) {
      uintx2 pk;
      pk.x = pkbf(o[s][dt][0] * inv, o[s][dt][1] * inv);
      pk.y = pkbf(o[s][dt][2] * inv, o[s][dt][3] * inv);
      *(uintx2*)(dst + dt * 16) = pk;
    }
  }
}

// ---------------- residual + LayerNorm ----------------
__global__ __launch_bounds__(256) void ln_kernel(const float* __restrict__ aout,
                                                 const float* __restrict__ x,
                                                 const float* __restrict__ gamma,
                                                 const float* __restrict__ beta,
                                                 float* __restrict__ out) {
  int row = blockIdx.x;
  int t = threadIdx.x;
  const float4* a4 = (const float4*)(aout + (size_t)row * 1024);
  const float4* x4 = (const float4*)(x + (size_t)row * 1024);
  float4 v = a4[t];
  float4 xv = x4[t];
  v.x += xv.x; v.y += xv.y; v.z += xv.z; v.w += xv.w;
  float s = v.x + v.y + v.z + v.w;
  float s2 = v.x * v.x + v.y * v.y + v.z * v.z + v.w * v.w;
  for (int off = 1; off < 64; off <<= 1) {
    s += __shfl_xor(s, off, 64);
    s2 += __shfl_xor(s2, off, 64);
  }
  __shared__ float red[8];
  int wave = t >> 6, lane = t & 63;
  if (lane == 0) { red[wave] = s; red[4 + wave] = s2; }
  __syncthreads();
  s = red[0] + red[1] + red[2] + red[3];
  s2 = red[4] + red[5] + red[6] + red[7];
  float mu = s * (1.0f / 1024.0f);
  float var = s2 * (1.0f / 1024.0f) - mu * mu;
  float rstd = rsqrtf(var + 1e-5f);
  float4 g = ((const float4*)gamma)[t];
  float4 be = ((const float4*)beta)[t];
  float4 y;
  y.x = (v.x - mu) * rstd * g.x + be.x;
  y.y = (v.y - mu) * rstd * g.y + be.y;
  y.z = (v.z - mu) * rstd * g.z + be.z;
  y.w = (v.w - mu) * rstd * g.w + be.w;
  ((float4*)(out + (size_t)row * 1024))[t] = y;
}

extern "C" void kernel_launch(void* const* d_in, const int* in_sizes, int n_in,
                              void* d_out, int out_size, void* d_ws, size_t ws_size,
                              hipStream_t stream) {
  const float* x     = (const float*)d_in[0];
  const float* Wq    = (const float*)d_in[1];
  const float* bq    = (const float*)d_in[2];
  const float* Wk    = (const float*)d_in[3];
  const float* bk    = (const float*)d_in[4];
  const float* Wv    = (const float*)d_in[5];
  const float* bv    = (const float*)d_in[6];
  const float* Wo    = (const float*)d_in[7];
  const float* bo    = (const float*)d_in[8];
  const float* gamma = (const float*)d_in[9];
  const float* beta  = (const float*)d_in[10];
  float* out = (float*)d_out;

  char* ws = (char*)d_ws;
  u16* xb   = (u16*)(ws);
  u16* Wt   = (u16*)(ws + ((size_t)8 << 20));
  u16* Qh   = (u16*)(ws + ((size_t)16 << 20));
  u16* Kh   = (u16*)(ws + ((size_t)24 << 20));
  u16* Vth  = (u16*)(ws + ((size_t)32 << 20));
  u16* ctx  = (u16*)(ws + ((size_t)40 << 20));
  float* aout = (float*)(ws + ((size_t)48 << 20));

  prep_kernel<<<8192, 256, 0, stream>>>(x, xb, Wq, Wk, Wv, Wo, Wt);
  qkv_gemm<<<dim3(16, 12), 512, 0, stream>>>(xb, Wt, bq, bk, bv, Qh, Kh, Vth);
  attn_kernel<<<dim3(32, 16), 256, 0, stream>>>(Qh, Kh, Vth, ctx);
  out_gemm<<<dim3(32, 16), 256, 0, stream>>>(ctx, Wt + (size_t)3 * 1024 * 1024, bo, aout);
  ln_kernel<<<4096, 256, 0, stream>>>(aout, x, gamma, beta, out);
}

// Round 5
// 192.967 us; speedup vs baseline: 1.0485x; 1.0485x over previous
//
#include <hip/hip_runtime.h>

typedef unsigned short u16;
typedef __attribute__((ext_vector_type(8))) short shortx8;
typedef __attribute__((ext_vector_type(4))) float floatx4;
typedef __attribute__((ext_vector_type(2))) float floatx2;
typedef __attribute__((ext_vector_type(2))) unsigned uintx2;
typedef __attribute__((ext_vector_type(4))) unsigned uintx4;

#define GLD16(gp, lp) __builtin_amdgcn_global_load_lds( \
    (__attribute__((address_space(1))) void*)(gp), \
    (__attribute__((address_space(3))) void*)(lp), 16, 0, 0)

#define BAR() __builtin_amdgcn_s_barrier()
#define LGKM0() do { asm volatile("s_waitcnt lgkmcnt(0)" ::: "memory"); \
                     __builtin_amdgcn_sched_barrier(0); } while (0)
#define VMCNT0() do { asm volatile("s_waitcnt vmcnt(0)" ::: "memory"); \
                      __builtin_amdgcn_sched_barrier(0); } while (0)

__device__ __forceinline__ u16 f2bf(float f) {
  union { float f; unsigned u; } v; v.f = f;
  unsigned r = v.u + 0x7FFFu + ((v.u >> 16) & 1u);
  return (u16)(r >> 16);
}

// pack two f32 -> bf16x2 in one u32 (low = a, high = b)
__device__ __forceinline__ unsigned pkbf(float a, float b) {
#if __has_builtin(__builtin_amdgcn_cvt_pk_bf16_f32)
  auto r = __builtin_amdgcn_cvt_pk_bf16_f32(a, b);
  return __builtin_bit_cast(unsigned, r);
#else
  union { float f; unsigned u; } x, y; x.f = a; y.f = b;
  return __builtin_amdgcn_perm(y.u + 0x8000u, x.u + 0x8000u, 0x07060302u);
#endif
}

// ---------------- prep: cast x -> bf16  +  transpose-cast 4 weights ----------------
__global__ __launch_bounds__(256) void prep_kernel(const float* __restrict__ x,
                                                   u16* __restrict__ xb,
                                                   const float* __restrict__ Wq,
                                                   const float* __restrict__ Wk,
                                                   const float* __restrict__ Wv,
                                                   const float* __restrict__ Wo,
                                                   u16* __restrict__ Wt) {
  __shared__ u16 tile[32][33];
  int bid = blockIdx.x;
  int tid = threadIdx.x;
  if (bid < 4096) {
    int i = bid * 256 + tid;
    float4 v = ((const float4*)x)[i];
    uintx2 o;
    o.x = pkbf(v.x, v.y);
    o.y = pkbf(v.z, v.w);
    ((uintx2*)xb)[i] = o;
  } else {
    int block = bid - 4096;
    int mat = block >> 10;
    int rem = block & 1023;
    const float* W = (mat == 0) ? Wq : (mat == 1) ? Wk : (mat == 2) ? Wv : Wo;
    u16* dst = Wt + (size_t)mat * 1024 * 1024;
    int n0 = (rem & 31) * 32, k0 = (rem >> 5) * 32;
    int tx = tid & 31, ty = tid >> 5;
    for (int i = 0; i < 4; ++i)
      tile[ty + i * 8][tx] = f2bf(W[(size_t)(k0 + ty + i * 8) * 1024 + n0 + tx]);
    __syncthreads();
    for (int i = 0; i < 4; ++i)
      dst[(size_t)(n0 + ty + i * 8) * 1024 + k0 + tx] = tile[tx][ty + i * 8];
  }
}

// ---------------- QKV projection: 256x256-tile 8-phase schedule ----------------
template <int MIB>
__device__ __forceinline__ void qkv_lda(const u16* Ah, int lrow, int lcol,
                                        shortx8 (&afr)[2][2]) {
#pragma unroll
  for (int j = 0; j < 2; ++j) {
    int rm = (MIB + j) * 16 + lcol;
#pragma unroll
    for (int kk = 0; kk < 2; ++kk)
      afr[j][kk] = *(const shortx8*)&Ah[rm * 64 + (((kk * 4 + lrow) ^ (rm & 7)) * 8)];
  }
}

template <int MIB>
__device__ __forceinline__ void qkv_mfma(floatx4 (&acc)[8][4],
                                         const shortx8 (&afr)[2][2],
                                         const shortx8 (&bfr)[4][2]) {
#pragma unroll
  for (int kk = 0; kk < 2; ++kk)
#pragma unroll
    for (int j = 0; j < 2; ++j)
#pragma unroll
      for (int ni = 0; ni < 4; ++ni)
        acc[MIB + j][ni] = __builtin_amdgcn_mfma_f32_16x16x32_bf16(
            afr[j][kk], bfr[ni][kk], acc[MIB + j][ni], 0, 0, 0);
}

__global__ __launch_bounds__(512, 2) void qkv_gemm(const u16* __restrict__ xb,
                                                   const u16* __restrict__ Wt,
                                                   const float* __restrict__ bq,
                                                   const float* __restrict__ bk,
                                                   const float* __restrict__ bv,
                                                   u16* __restrict__ Qh,
                                                   u16* __restrict__ Kh,
                                                   u16* __restrict__ Vth) {
  __shared__ u16 lds[65536];   // dbuf d: A at d*32768, B at d*32768+16384 (u16 units)
  const int tid = threadIdx.x;
  const int wave = tid >> 6, lane = tid & 63;
  const int lrow = lane >> 4, lcol = lane & 15;
  const int wm = wave >> 2, wn = wave & 3;
  const int m0 = blockIdx.x * 256;
  const int nt = blockIdx.y;
  const int mat = nt >> 2;
  const int n0 = (nt & 3) * 256;
  const u16* Ag = xb;
  const u16* Bg = Wt + (size_t)mat * 1048576;

  const u16* sa[2][2];
  const u16* sb[2][2];
#pragma unroll
  for (int h = 0; h < 2; ++h)
#pragma unroll
    for (int l = 0; l < 2; ++l) {
      int g = (l * 8 + wave) * 64 + lane;
      int r = g >> 3, c = g & 7;
      int cc = (c ^ (r & 7)) * 8;
      sa[h][l] = Ag + (size_t)(m0 + h * 128 + r) * 1024 + cc;
      sb[h][l] = Bg + (size_t)(n0 + h * 128 + r) * 1024 + cc;
    }

  floatx4 acc[8][4];
#pragma unroll
  for (int mi = 0; mi < 8; ++mi)
#pragma unroll
    for (int ni = 0; ni < 4; ++ni)
      acc[mi][ni] = (floatx4){0.f, 0.f, 0.f, 0.f};

  // prologue: stage K-tile 0 into dbuf 0
#pragma unroll
  for (int h = 0; h < 2; ++h)
#pragma unroll
    for (int l = 0; l < 2; ++l) {
      GLD16(sa[h][l], lds + h * 8192 + (l * 8 + wave) * 512);
      GLD16(sb[h][l], lds + 16384 + h * 8192 + (l * 8 + wave) * 512);
    }
  VMCNT0();
  BAR();

#pragma unroll 2
  for (int t = 0; t < 16; ++t) {
    const int rb = t & 1, wb = rb ^ 1;
    const u16* Ah = lds + rb * 32768 + wm * 8192;
    const u16* Bh = lds + rb * 32768 + 16384 + (wn >> 1) * 8192;
    u16* Aw = lds + wb * 32768;
    u16* Bw = lds + wb * 32768 + 16384;

    // ---- phase 0: stage A halves of t+1; read all B-frags + A-frags mi 0-1
    if (t < 15) {
      int k64 = (t + 1) * 64;
#pragma unroll
      for (int l = 0; l < 2; ++l) {
        GLD16(sa[0][l] + k64, Aw + (l * 8 + wave) * 512);
        GLD16(sa[1][l] + k64, Aw + 8192 + (l * 8 + wave) * 512);
      }
    }
    shortx8 bfr[4][2];
#pragma unroll
    for (int ni = 0; ni < 4; ++ni) {
      int rn = (wn & 1) * 64 + ni * 16 + lcol;
#pragma unroll
      for (int kk = 0; kk < 2; ++kk)
        bfr[ni][kk] = *(const shortx8*)&Bh[rn * 64 + (((kk * 4 + lrow) ^ (rn & 7)) * 8)];
    }
    {
      shortx8 afr[2][2];
      qkv_lda<0>(Ah, lrow, lcol, afr);
      BAR();
      LGKM0();
      __builtin_amdgcn_s_setprio(1);
      qkv_mfma<0>(acc, afr, bfr);
      __builtin_amdgcn_s_setprio(0);
      BAR();
    }
    // ---- phase 1: stage B halves of t+1; A-frags mi 2-3
    if (t < 15) {
      int k64 = (t + 1) * 64;
#pragma unroll
      for (int l = 0; l < 2; ++l) {
        GLD16(sb[0][l] + k64, Bw + (l * 8 + wave) * 512);
        GLD16(sb[1][l] + k64, Bw + 8192 + (l * 8 + wave) * 512);
      }
    }
    {
      shortx8 afr[2][2];
      qkv_lda<2>(Ah, lrow, lcol, afr);
      BAR();
      LGKM0();
      __builtin_amdgcn_s_setprio(1);
      qkv_mfma<2>(acc, afr, bfr);
      __builtin_amdgcn_s_setprio(0);
      BAR();
    }
    // ---- phase 2: A-frags mi 4-5
    {
      shortx8 afr[2][2];
      qkv_lda<4>(Ah, lrow, lcol, afr);
      BAR();
      LGKM0();
      __builtin_amdgcn_s_setprio(1);
      qkv_mfma<4>(acc, afr, bfr);
      __builtin_amdgcn_s_setprio(0);
      BAR();
    }
    // ---- phase 3: A-frags mi 6-7; boundary vmcnt drains t+1 loads (~3 phases old)
    {
      shortx8 afr[2][2];
      qkv_lda<6>(Ah, lrow, lcol, afr);
      BAR();
      LGKM0();
      __builtin_amdgcn_s_setprio(1);
      qkv_mfma<6>(acc, afr, bfr);
      __builtin_amdgcn_s_setprio(0);
      VMCNT0();
      BAR();
    }
  }

  // ---------------- epilogue ----------------
  const float* bias = (mat == 0) ? bq : (mat == 1) ? bk : bv;
  const float qscale = 0.18033688011f;  // log2(e)/8

  if (mat < 2) {
    // transpose-pack through the dead 128KiB LDS -> packed 16B stores
    u16* dst = (mat == 0) ? Qh : Kh;
    float sc = (mat == 0) ? qscale : 1.0f;
#pragma unroll
    for (int mi = 0; mi < 8; ++mi) {
      int mb = wm * 128 + mi * 16 + lrow * 4;
#pragma unroll
      for (int ni = 0; ni < 4; ++ni) {
        int n = wn * 64 + ni * 16 + lcol;
        float bval = bias[n0 + n];
#pragma unroll
        for (int r = 0; r < 4; ++r) {
          int m = mb + r;
          lds[m * 256 + (((n >> 3) ^ (m & 31)) * 8) + (n & 7)] =
              f2bf((acc[mi][ni][r] + bval) * sc);
        }
      }
    }
    __syncthreads();
    int row = tid >> 1, half = tid & 1;
    int m = m0 + row;
    int bb = m >> 11, s = m & 2047;
#pragma unroll
    for (int i = 0; i < 16; ++i) {
      int cg = half * 16 + i;                    // column granule (8 cols)
      int pg = cg ^ (row & 31);
      shortx8 v = *(const shortx8*)&lds[row * 256 + pg * 8];
      int ng = n0 + cg * 8;
      int hh = ng >> 6, d = ng & 63;
      *(shortx8*)&dst[((size_t)(bb * 16 + hh) * 2048 + s) * 64 + d] = v;
    }
  } else {
    // V: transposed scattered stores (head-major [bh][d][s])
#pragma unroll
    for (int mi = 0; mi < 8; ++mi) {
      int mbase = m0 + wm * 128 + mi * 16 + lrow * 4;
      int bb = mbase >> 11, s = mbase & 2047;
#pragma unroll
      for (int ni = 0; ni < 4; ++ni) {
        int n = n0 + wn * 64 + ni * 16 + lcol;
        float bval = bias[n];
        int hh = n >> 6, d = n & 63;
        uintx2 pk;
        pk.x = pkbf(acc[mi][ni][0] + bval, acc[mi][ni][1] + bval);
        pk.y = pkbf(acc[mi][ni][2] + bval, acc[mi][ni][3] + bval);
        *(uintx2*)&Vth[((size_t)(bb * 16 + hh) * 64 + d) * 2048 + s] = pk;
      }
    }
  }
}

// ---------------- output projection: aout = ctx @ Wo^T + bo (fp32) ----------------
// 128x64 tile, 512 blocks (2/CU), 2-phase counted-vmcnt schedule (qkv pattern):
// prefetch t+1 issued in both phases into the write-dbuf; single VMCNT0 at the
// tile boundary (~1.5 phases of slack); raw barriers + lgkmcnt(0) only.
__global__ __launch_bounds__(256, 2) void out_gemm(const u16* __restrict__ ctx,
                                                   const u16* __restrict__ Wot,
                                                   const float* __restrict__ bo,
                                                   float* __restrict__ aout) {
  __shared__ u16 lds[24576];   // dbuf d: A(128x64) at d*12288, B(64x64) at d*12288+8192
  const int tid = threadIdx.x;
  const int wave = tid >> 6, lane = tid & 63;
  const int lrow = lane >> 4, lcol = lane & 15;
  const int wm = wave >> 1, wn = wave & 1;
  const int m0 = blockIdx.x * 128;
  const int n0 = blockIdx.y * 64;

  const u16* sa[4];
  const u16* sb[2];
#pragma unroll
  for (int l = 0; l < 4; ++l) {
    int g = (l * 4 + wave) * 64 + lane;
    int r = g >> 3, c = g & 7;
    sa[l] = ctx + (size_t)(m0 + r) * 1024 + ((c ^ (r & 7)) * 8);
  }
#pragma unroll
  for (int l = 0; l < 2; ++l) {
    int g = (l * 4 + wave) * 64 + lane;
    int r = g >> 3, c = g & 7;
    sb[l] = Wot + (size_t)(n0 + r) * 1024 + ((c ^ (r & 7)) * 8);
  }

  floatx4 acc[4][2];
#pragma unroll
  for (int mi = 0; mi < 4; ++mi)
#pragma unroll
    for (int ni = 0; ni < 2; ++ni)
      acc[mi][ni] = (floatx4){0.f, 0.f, 0.f, 0.f};

  // prologue: stage K-tile 0 into dbuf 0
#pragma unroll
  for (int l = 0; l < 4; ++l) GLD16(sa[l], lds + (l * 4 + wave) * 512);
#pragma unroll
  for (int l = 0; l < 2; ++l) GLD16(sb[l], lds + 8192 + (l * 4 + wave) * 512);
  VMCNT0();
  BAR();

#pragma unroll 2
  for (int t = 0; t < 16; ++t) {
    const int rb = t & 1, wb = rb ^ 1;
    const u16* Ab = lds + rb * 12288;
    const u16* Bb = lds + rb * 12288 + 8192;
    u16* Aw = lds + wb * 12288;
    u16* Bw = lds + wb * 12288 + 8192;
    const int k64 = (t + 1) * 64;

    // ---- phase 0: prefetch A(t+1); read bfr (held across phases) + afr mi 0-1
    if (t < 15) {
#pragma unroll
      for (int l = 0; l < 4; ++l) GLD16(sa[l] + k64, Aw + (l * 4 + wave) * 512);
    }
    shortx8 bfr[2][2];
#pragma unroll
    for (int ni = 0; ni < 2; ++ni) {
      int rn = wn * 32 + ni * 16 + lcol;
#pragma unroll
      for (int kk = 0; kk < 2; ++kk)
        bfr[ni][kk] = *(const shortx8*)&Bb[rn * 64 + (((kk * 4 + lrow) ^ (rn & 7)) * 8)];
    }
    {
      shortx8 afr[2][2];
#pragma unroll
      for (int j = 0; j < 2; ++j) {
        int rm = wm * 64 + j * 16 + lcol;
#pragma unroll
        for (int kk = 0; kk < 2; ++kk)
          afr[j][kk] = *(const shortx8*)&Ab[rm * 64 + (((kk * 4 + lrow) ^ (rm & 7)) * 8)];
      }
      BAR();
      LGKM0();
      __builtin_amdgcn_s_setprio(1);
#pragma unroll
      for (int kk = 0; kk < 2; ++kk)
#pragma unroll
        for (int j = 0; j < 2; ++j)
#pragma unroll
          for (int ni = 0; ni < 2; ++ni)
            acc[j][ni] = __builtin_amdgcn_mfma_f32_16x16x32_bf16(
                afr[j][kk], bfr[ni][kk], acc[j][ni], 0, 0, 0);
      __builtin_amdgcn_s_setprio(0);
      BAR();
    }
    // ---- phase 1: prefetch B(t+1); afr mi 2-3; boundary vmcnt drains t+1 loads
    if (t < 15) {
#pragma unroll
      for (int l = 0; l < 2; ++l) GLD16(sb[l] + k64, Bw + (l * 4 + wave) * 512);
    }
    {
      shortx8 afr[2][2];
#pragma unroll
      for (int j = 0; j < 2; ++j) {
        int rm = wm * 64 + (2 + j) * 16 + lcol;
#pragma unroll
        for (int kk = 0; kk < 2; ++kk)
          afr[j][kk] = *(const shortx8*)&Ab[rm * 64 + (((kk * 4 + lrow) ^ (rm & 7)) * 8)];
      }
      BAR();
      LGKM0();
      __builtin_amdgcn_s_setprio(1);
#pragma unroll
      for (int kk = 0; kk < 2; ++kk)
#pragma unroll
        for (int j = 0; j < 2; ++j)
#pragma unroll
          for (int ni = 0; ni < 2; ++ni)
            acc[2 + j][ni] = __builtin_amdgcn_mfma_f32_16x16x32_bf16(
                afr[j][kk], bfr[ni][kk], acc[2 + j][ni], 0, 0, 0);
      __builtin_amdgcn_s_setprio(0);
      VMCNT0();
      BAR();
    }
  }

#pragma unroll
  for (int mi = 0; mi < 4; ++mi) {
    int mbase = m0 + wm * 64 + mi * 16 + lrow * 4;
#pragma unroll
    for (int ni = 0; ni < 2; ++ni) {
      int n = n0 + wn * 32 + ni * 16 + lcol;
      float bval = bo[n];
#pragma unroll
      for (int r = 0; r < 4; ++r)
        aout[(size_t)(mbase + r) * 1024 + n] = acc[mi][ni][r] + bval;
    }
  }
}

// ---------------- flash attention (R2-proven version, 46.0 us) ----------------
// grid (32_bh, 16_qt), 512 threads (8 waves x 16 q-rows). LDS 48KB.
// P never touches LDS (QK^T accumulator pairs feed the PV B-fragment in-order;
// V staged with inverse-permuted key columns). Row-sums via ones-MFMA.
__global__ __launch_bounds__(512) void attn_kernel(const u16* __restrict__ Qh,
                                                   const u16* __restrict__ Kh,
                                                   const u16* __restrict__ Vth,
                                                   u16* __restrict__ ctx) {
  __shared__ u16 QPs[128 * 64];     // Q tile staging (dead after prologue)
  __shared__ u16 Ks[2][64 * 64];
  __shared__ u16 Vs[2][64 * 64];

  int bh = blockIdx.x;
  int b = bh >> 4, h = bh & 15;
  int q0 = blockIdx.y * 128;
  int tid = threadIdx.x;
  int wave = tid >> 6, lane = tid & 63;
  int lrow = lane >> 4, lcol = lane & 15;

  const u16* Qg = Qh + ((size_t)bh * 2048 + q0) * 64;
  for (int l = 0; l < 2; ++l) {
    int g = (l * 8 + wave) * 64 + lane;
    int r = g >> 3, c = g & 7;
    GLD16(Qg + r * 64 + ((c ^ (r & 7)) * 8), QPs + (l * 8 + wave) * 512);
  }

  const u16* Kbase = Kh + (size_t)bh * 2048 * 64;
  const u16* Vbase = Vth + (size_t)bh * 64 * 2048;

  int g = wave * 64 + lane;
  int gr = g >> 3, gc = g & 7;
  int cc = (gc ^ (gr & 7)) * 8;
  const u16* kp = Kbase + (size_t)gr * 64 + cc;

  const u16* vp = Vbase + (size_t)gr * 2048 + gc * 8;
  int hh = gc >> 2, ct = gc & 3;
  int ua = 4 * (ct & 1) + (ct >> 1);
  int chunkA = hh * 4 + (ua >> 1);
  int offA = gr * 128 + ((chunkA ^ (gr & 7)) * 16) + (ua & 1) * 8;
  int offB = gr * 128 + (((chunkA + 1) ^ (gr & 7)) * 16) + (ua & 1) * 8;

  // prologue: tile 0
  {
    float4 vreg = *(const float4*)vp;
    vp += 64;
    GLD16(kp, (u16*)Ks + wave * 512);
    kp += 4096;
    char* vb = (char*)Vs;
    *(floatx2*)(vb + offA) = (floatx2){vreg.x, vreg.y};
    *(floatx2*)(vb + offB) = (floatx2){vreg.z, vreg.w};
  }
  __syncthreads();

  // hoist Q fragments (B-operand: n = q = lane&15); wave owns q-rows wave*16..+15
  shortx8 qf[2];
  for (int kk = 0; kk < 2; ++kk) {
    int row = wave * 16 + lcol;
    int grr = (kk * 4 + lrow) ^ (row & 7);
    qf[kk] = *(const shortx8*)&QPs[row * 64 + grr * 8];
  }

  const short one_bf = (short)0x3F80;
  const shortx8 ones8 = {one_bf, one_bf, one_bf, one_bf, one_bf, one_bf, one_bf, one_bf};

  floatx4 o[4];
  floatx4 lacc = (floatx4){0.f, 0.f, 0.f, 0.f};
  for (int dt = 0; dt < 4; ++dt) o[dt] = (floatx4){0.f, 0.f, 0.f, 0.f};

  for (int i = 0; i < 32; ++i) {
    int cur = i & 1;
    float4 vreg;
    if (i < 31) {
      vreg = *(const float4*)vp;   // issued before K GLD so vmcnt-wait keeps K in flight
      vp += 64;
      GLD16(kp, (u16*)Ks + (cur ^ 1) * 4096 + wave * 512);
      kp += 4096;
    }

    // S^T[key][q] for this wave's 16 q-cols x 64 keys
    floatx4 sc[4];
    for (int kt = 0; kt < 4; ++kt)
      sc[kt] = (floatx4){0.f, 0.f, 0.f, 0.f};
    __builtin_amdgcn_s_setprio(1);
    for (int kk = 0; kk < 2; ++kk) {
      for (int kt = 0; kt < 4; ++kt) {
        int row = kt * 16 + lcol;
        int grr = (kk * 4 + lrow) ^ (row & 7);
        shortx8 kf = *(const shortx8*)&Ks[cur][row * 64 + grr * 8];
        sc[kt] = __builtin_amdgcn_mfma_f32_16x16x32_bf16(kf, qf[kk], sc[kt], 0, 0, 0);
      }
    }
    __builtin_amdgcn_s_setprio(0);

    // P = exp2(S^T) (Q pre-scaled); pack in-register into B-fragments.
    float p[4][4];
    for (int kt = 0; kt < 4; ++kt)
      for (int r = 0; r < 4; ++r)
        p[kt][r] = __builtin_amdgcn_exp2f(sc[kt][r]);
    shortx8 pf[2];
    for (int kk = 0; kk < 2; ++kk) {
      uintx4 w;
      w.x = pkbf(p[2 * kk][0], p[2 * kk][1]);
      w.y = pkbf(p[2 * kk][2], p[2 * kk][3]);
      w.z = pkbf(p[2 * kk + 1][0], p[2 * kk + 1][1]);
      w.w = pkbf(p[2 * kk + 1][2], p[2 * kk + 1][3]);
      pf[kk] = __builtin_bit_cast(shortx8, w);
    }

    // stage next V tile (permuted columns) while PV covers the lgkm latency
    if (i < 31) {
      char* vb = (char*)Vs + (cur ^ 1) * 8192;
      *(floatx2*)(vb + offA) = (floatx2){vreg.x, vreg.y};
      *(floatx2*)(vb + offB) = (floatx2){vreg.z, vreg.w};
    }

    // O^T += V^T P^T; row-sums l += ones * P^T (same pf operand)
    __builtin_amdgcn_s_setprio(1);
    for (int kk = 0; kk < 2; ++kk) {
      lacc = __builtin_amdgcn_mfma_f32_16x16x32_bf16(ones8, pf[kk], lacc, 0, 0, 0);
      for (int dt = 0; dt < 4; ++dt) {
        int row = dt * 16 + lcol;
        int grr = (kk * 4 + lrow) ^ (row & 7);
        shortx8 vf = *(const shortx8*)&Vs[cur][row * 64 + grr * 8];
        o[dt] = __builtin_amdgcn_mfma_f32_16x16x32_bf16(vf, pf[kk], o[dt], 0, 0, 0);
      }
    }
    __builtin_amdgcn_s_setprio(0);
    __syncthreads();
  }

  // epilogue: l = lacc[0] (all regs equal = column sum), O /= l, packed 8B stores
  {
    float inv = 1.0f / lacc[0];
    int s = q0 + wave * 16 + lcol;
    u16* dst = ctx + (size_t)(b * 2048 + s) * 1024 + h * 64 + lrow * 4;
    for (int dt = 0; dt < 4; ++dt) {
      uintx2 pk;
      pk.x = pkbf(o[dt][0] * inv, o[dt][1] * inv);
      pk.y = pkbf(o[dt][2] * inv, o[dt][3] * inv);
      *(uintx2*)(dst + dt * 16) = pk;
    }
  }
}

// ---------------- residual + LayerNorm ----------------
__global__ __launch_bounds__(256) void ln_kernel(const float* __restrict__ aout,
                                                 const float* __restrict__ x,
                                                 const float* __restrict__ gamma,
                                                 const float* __restrict__ beta,
                                                 float* __restrict__ out) {
  int row = blockIdx.x;
  int t = threadIdx.x;
  const float4* a4 = (const float4*)(aout + (size_t)row * 1024);
  const float4* x4 = (const float4*)(x + (size_t)row * 1024);
  float4 v = a4[t];
  float4 xv = x4[t];
  v.x += xv.x; v.y += xv.y; v.z += xv.z; v.w += xv.w;
  float s = v.x + v.y + v.z + v.w;
  float s2 = v.x * v.x + v.y * v.y + v.z * v.z + v.w * v.w;
  for (int off = 1; off < 64; off <<= 1) {
    s += __shfl_xor(s, off, 64);
    s2 += __shfl_xor(s2, off, 64);
  }
  __shared__ float red[8];
  int wave = t >> 6, lane = t & 63;
  if (lane == 0) { red[wave] = s; red[4 + wave] = s2; }
  __syncthreads();
  s = red[0] + red[1] + red[2] + red[3];
  s2 = red[4] + red[5] + red[6] + red[7];
  float mu = s * (1.0f / 1024.0f);
  float var = s2 * (1.0f / 1024.0f) - mu * mu;
  float rstd = rsqrtf(var + 1e-5f);
  float4 g = ((const float4*)gamma)[t];
  float4 be = ((const float4*)beta)[t];
  float4 y;
  y.x = (v.x - mu) * rstd * g.x + be.x;
  y.y = (v.y - mu) * rstd * g.y + be.y;
  y.z = (v.z - mu) * rstd * g.z + be.z;
  y.w = (v.w - mu) * rstd * g.w + be.w;
  ((float4*)(out + (size_t)row * 1024))[t] = y;
}

extern "C" void kernel_launch(void* const* d_in, const int* in_sizes, int n_in,
                              void* d_out, int out_size, void* d_ws, size_t ws_size,
                              hipStream_t stream) {
  const float* x     = (const float*)d_in[0];
  const float* Wq    = (const float*)d_in[1];
  const float* bq    = (const float*)d_in[2];
  const float* Wk    = (const float*)d_in[3];
  const float* bk    = (const float*)d_in[4];
  const float* Wv    = (const float*)d_in[5];
  const float* bv    = (const float*)d_in[6];
  const float* Wo    = (const float*)d_in[7];
  const float* bo    = (const float*)d_in[8];
  const float* gamma = (const float*)d_in[9];
  const float* beta  = (const float*)d_in[10];
  float* out = (float*)d_out;

  char* ws = (char*)d_ws;
  u16* xb   = (u16*)(ws);
  u16* Wt   = (u16*)(ws + ((size_t)8 << 20));
  u16* Qh   = (u16*)(ws + ((size_t)16 << 20));
  u16* Kh   = (u16*)(ws + ((size_t)24 << 20));
  u16* Vth  = (u16*)(ws + ((size_t)32 << 20));
  u16* ctx  = (u16*)(ws + ((size_t)40 << 20));
  float* aout = (float*)(ws + ((size_t)48 << 20));

  prep_kernel<<<8192, 256, 0, stream>>>(x, xb, Wq, Wk, Wv, Wo, Wt);
  qkv_gemm<<<dim3(16, 12), 512, 0, stream>>>(xb, Wt, bq, bk, bv, Qh, Kh, Vth);
  attn_kernel<<<dim3(32, 16), 512, 0, stream>>>(Qh, Kh, Vth, ctx);
  out_gemm<<<dim3(32, 16), 256, 0, stream>>>(ctx, Wt + (size_t)3 * 1024 * 1024, bo, aout);
  ln_kernel<<<4096, 256, 0, stream>>>(aout, x, gamma, beta, out);
}